// Round 13
// baseline (27.152 us; speedup 1.0000x reference)
//
#include <hip/hip_runtime.h>

// AdLIF neuron scan, fused symmetric-hybrid pipeline (round 13).
//
// Mechanism targeted: __syncthreads emits `s_waitcnt vmcnt(0)` before every
// s_barrier, so each of r10's 9 periods serially paid the ~900cy ack latency
// of its last global op (~13% of the period -- exactly the measured gap to
// the copy roofline). All cross-wave deps here have >= 1 period of slack
// (tile ds_written in period k, consumed k+1; sbits written k, read k+1),
// so the barrier only needs lgkmcnt(0), never a global drain.
//
// 512 blocks x 512 threads (8 waves), one block owns 64 channels:
//   ALL 8 waves each period (symmetric roles, counted-FIFO order):
//     1. issue 2 dwordx4 loads of tile k+2 -> regs        (FIFO: oldest)
//     2. ds_write last period's regs (tile k+1) to LDS    (vmcnt counted ~4)
//     3. wave 0 only: 64-step recurrence on tile k from LDS -> sbits[k&1]
//     4. expand sbits[(k-1)&1] -> 2 f32x4 NT stores       (never waited on)
//     5. lgkmcnt(0); sched_barrier; raw s_barrier  (NO vmcnt drain)
//   LDS: 2-slot tile ring (3rd "slot" lives in registers) + sbits = ~35 KB.
//
// FP order matches the JAX reference exactly (mul then add, round-to-nearest,
// NO fma contraction) so spike decisions are bit-stable vs the reference.

#define T_STEPS 512
#define D_DIM   1024
#define T_TILE  64
#define N_TILES (T_STEPS / T_TILE)   // 8
#define LDS_PITCH 66                 // 64 + 2 pad (dwords)

// f32(np.exp(-1/20)), f32(np.exp(-1/200))
#define ALPHA_MEM 0.9512294245007141f
#define ALPHA_ADP 0.9950124791926823f

typedef float f32x4 __attribute__((ext_vector_type(4)));

__device__ __forceinline__ bool adlif_step(float xv, float& v, float& a) {
    // v = alpha_mem * v + x_t
    v = __fadd_rn(__fmul_rn(ALPHA_MEM, v), xv);
    // cur_thr = THRESHOLD + BETA * a  (1.0 + 0.1*a)
    float cur = __fadd_rn(1.0f, __fmul_rn(0.1f, a));
    // s = (v - cur_thr >= THRESHOLD)   -- threshold counts twice, per ref
    float u = __fsub_rn(v, cur);
    bool fired = (u >= 1.0f);
    float s = fired ? 1.0f : 0.0f;
    // a = alpha_adp * a + s
    a = __fadd_rn(__fmul_rn(ALPHA_ADP, a), s);
    // v = v - s * THRESHOLD  (THRESHOLD = 1, exact)
    v = __fsub_rn(v, s);
    return fired;
}

#define BARRIER_LGKM_ONLY() do {                                   \
    asm volatile("s_waitcnt lgkmcnt(0)" ::: "memory");             \
    __builtin_amdgcn_sched_barrier(0);                             \
    __builtin_amdgcn_s_barrier();                                  \
    __builtin_amdgcn_sched_barrier(0);                             \
} while (0)

__global__ __launch_bounds__(512) void adlif_fused(const float* __restrict__ x,
                                                   float* __restrict__ out) {
    __shared__ float    tiles[2][T_TILE][LDS_PITCH]; // 33.8 KB, 2-slot ring
    __shared__ unsigned sbits[2][64][2];             // 1 KB spike-bit dbuf

    const int lane = threadIdx.x & 63;
    const int wave = threadIdx.x >> 6;               // 0..7
    const int bid  = blockIdx.x;                     // 0..511
    const int b    = bid >> 4;                       // 0..31
    const int dgrp = bid & 15;                       // 0..15
    const float* xb = x   + (size_t)b * (T_STEPS * D_DIM) + dgrp * 64;
    float*       ob = out + (size_t)b * (T_STEPS * D_DIM) + dgrp * 64;

    const int rl = lane >> 4;                        // 0..3 row-within-instr
    const int c0 = (lane & 15) * 4;                  // 4 channels per lane
    const int ra = wave * 8 + rl;                    // this wave's row, instr 0
    const int rb = wave * 8 + 4 + rl;                // this wave's row, instr 1

    float v = 0.0f, a = 0.0f;

    // ---- prologue: tile 0 -> LDS, tile 1 -> regs (counted waits only) ----
    f32x4 ld0 = *reinterpret_cast<const f32x4*>(xb + (size_t)(0 * T_TILE + ra) * D_DIM + c0);
    f32x4 ld1 = *reinterpret_cast<const f32x4*>(xb + (size_t)(0 * T_TILE + rb) * D_DIM + c0);
    f32x4 p0  = *reinterpret_cast<const f32x4*>(xb + (size_t)(1 * T_TILE + ra) * D_DIM + c0);
    f32x4 p1  = *reinterpret_cast<const f32x4*>(xb + (size_t)(1 * T_TILE + rb) * D_DIM + c0);
    *reinterpret_cast<f32x4*>(&tiles[0][ra][c0]) = ld0;   // waits vmcnt(2), counted
    *reinterpret_cast<f32x4*>(&tiles[0][rb][c0]) = ld1;
    ld0 = p0;
    ld1 = p1;
    BARRIER_LGKM_ONLY();

    for (int k = 0; k <= N_TILES; ++k) {             // 9 pipelined periods
        // ---- 1. issue loads for tile k+2 (oldest FIFO entries this period) ----
        f32x4 nld0 = ld0, nld1 = ld1;
        const int t2 = k + 2;
        if (t2 < N_TILES) {
            nld0 = *reinterpret_cast<const f32x4*>(xb + (size_t)(t2 * T_TILE + ra) * D_DIM + c0);
            nld1 = *reinterpret_cast<const f32x4*>(xb + (size_t)(t2 * T_TILE + rb) * D_DIM + c0);
        }

        // ---- 2. ds_write tile k+1 from regs (counted vmcnt, no drain) ----
        if (k + 1 < N_TILES) {
            *reinterpret_cast<f32x4*>(&tiles[(k + 1) & 1][ra][c0]) = ld0;
            *reinterpret_cast<f32x4*>(&tiles[(k + 1) & 1][rb][c0]) = ld1;
        }

        // ---- 3. consumer (wave 0): 64 steps of tile k -> sbits[k&1] ----
        if (wave == 0 && k < N_TILES) {
            unsigned wlo = 0u, whi = 0u;
#pragma unroll
            for (int j = 0; j < T_TILE; ++j) {
                const float xv = tiles[k & 1][j][lane];
                const bool f = adlif_step(xv, v, a);
                if (j < 32) wlo |= ((unsigned)f) << j;
                else        whi |= ((unsigned)f) << (j - 32);
            }
            sbits[k & 1][lane][0] = wlo;
            sbits[k & 1][lane][1] = whi;
        }

        // ---- 4. expand tile k-1 bits -> f32, 2 NT float4 stores per wave ----
        if (k >= 1) {
            const int kt = k - 1;
            const int half = wave >> 2;              // rows <32 -> wlo, else whi
            const unsigned w0 = sbits[kt & 1][c0 + 0][half];
            const unsigned w1 = sbits[kt & 1][c0 + 1][half];
            const unsigned w2 = sbits[kt & 1][c0 + 2][half];
            const unsigned w3 = sbits[kt & 1][c0 + 3][half];
#pragma unroll
            for (int i = 0; i < 2; ++i) {
                const int r      = wave * 8 + i * 4 + rl;        // row in tile
                const int bitpos = (wave & 3) * 8 + i * 4 + rl;  // bit in half-word
                f32x4 val;
                val.x = (float)((w0 >> bitpos) & 1u);
                val.y = (float)((w1 >> bitpos) & 1u);
                val.z = (float)((w2 >> bitpos) & 1u);
                val.w = (float)((w3 >> bitpos) & 1u);
                __builtin_nontemporal_store(
                    val, (f32x4*)(ob + (size_t)(kt * T_TILE + r) * D_DIM + c0));
            }
        }

        ld0 = nld0;
        ld1 = nld1;

        // ---- 5. LDS-visibility barrier only -- NO vmcnt(0) drain ----
        BARRIER_LGKM_ONLY();
    }
}

extern "C" void kernel_launch(void* const* d_in, const int* in_sizes, int n_in,
                              void* d_out, int out_size, void* d_ws, size_t ws_size,
                              hipStream_t stream) {
    const float* x = (const float*)d_in[0];
    float* out = (float*)d_out;

    const int total = in_sizes[0];            // B*T*D = 16777216
    const int channels = total / T_STEPS;     // B*D  = 32768
    const int blocks = channels / 64;         // 512 blocks x 8 waves

    adlif_fused<<<blocks, 512, 0, stream>>>(x, out);
}

// Round 14
// 26.577 us; speedup vs baseline: 1.0217x; 1.0217x over previous
//
#include <hip/hip_runtime.h>

// AdLIF neuron scan, fused producer/consumer/writer single kernel.
// Round 14 = round 10 (best, 26.1 us) + sbits layout transpose
// ([2][64][2] -> [2][2][64]) to kill the 4-way writer-read bank conflict
// (393K conflict cycles in r10; stride-4-dword reads are 2-way = free).
//
// 512 blocks x 512 threads (8 waves), one block owns 64 channels (b, dgrp):
//   wave 0   : consumer -- 512-step recurrence reading x-tiles from a 3-deep
//              LDS ring, bitpacks spikes into a tiny LDS double-buffer.
//   waves 1-3: producers -- stage 64t x 64ch x-tiles into the ring with
//              dwordx4 loads (1 KB/instr), running 2 tiles ahead.
//   waves 4-7: writers -- expand tile k-1's bits to f32, float4 NT stores.
// One __syncthreads per tile; 9 pipelined iterations (8 tiles + drain).
//
// Steady state measured at ~91% of the m13 copy ceiling (9.4 vs 10.2
// B/cy/CU); residual is pipeline fill/drain. Structural probes that failed
// to beat this: more blocks/CU (r11), finer tiles + cooperative producers
// (r12), lgkm-only barriers (r13), counted-vmcnt register window (r7),
// two-kernel split (r6/r8).
//
// FP order matches the JAX reference exactly (mul then add, round-to-nearest,
// NO fma contraction) so spike decisions are bit-stable vs the reference.

#define T_STEPS 512
#define D_DIM   1024
#define T_TILE  64
#define N_TILES (T_STEPS / T_TILE)   // 8
#define RING    3
#define LDS_PITCH 66                 // 64 + 2 pad (dwords)

// f32(np.exp(-1/20)), f32(np.exp(-1/200))
#define ALPHA_MEM 0.9512294245007141f
#define ALPHA_ADP 0.9950124791926823f

typedef float f32x4 __attribute__((ext_vector_type(4)));

__device__ __forceinline__ bool adlif_step(float xv, float& v, float& a) {
    // v = alpha_mem * v + x_t
    v = __fadd_rn(__fmul_rn(ALPHA_MEM, v), xv);
    // cur_thr = THRESHOLD + BETA * a  (1.0 + 0.1*a)
    float cur = __fadd_rn(1.0f, __fmul_rn(0.1f, a));
    // s = (v - cur_thr >= THRESHOLD)   -- threshold counts twice, per ref
    float u = __fsub_rn(v, cur);
    bool fired = (u >= 1.0f);
    float s = fired ? 1.0f : 0.0f;
    // a = alpha_adp * a + s
    a = __fadd_rn(__fmul_rn(ALPHA_ADP, a), s);
    // v = v - s * THRESHOLD  (THRESHOLD = 1, exact)
    v = __fsub_rn(v, s);
    return fired;
}

// Producer: load one 64t x 64ch tile with 16 dwordx4 loads per wave.
// Lane L: rows r0=L>>4 (+4 per instr), channels m=(L&15)*4 .. +3.
__device__ __forceinline__ void load_tile(const float* __restrict__ xb, int t0,
                                          int lane, float (*buf)[LDS_PITCH]) {
    const int r0 = lane >> 4;            // 0..3
    const int m  = lane & 15;            // 0..15
    const float* src = xb + (size_t)(t0 + r0) * D_DIM + m * 4;
    f32x4 v[16];
#pragma unroll
    for (int i = 0; i < 16; ++i)
        v[i] = *reinterpret_cast<const f32x4*>(src + (size_t)i * 4 * D_DIM);
#pragma unroll
    for (int i = 0; i < 16; ++i)
        *reinterpret_cast<f32x4*>(&buf[i * 4 + r0][m * 4]) = v[i];
}

__global__ __launch_bounds__(512) void adlif_fused(const float* __restrict__ x,
                                                   float* __restrict__ out) {
    __shared__ float    tiles[RING][T_TILE][LDS_PITCH]; // 50688 B input ring
    __shared__ unsigned sbits[2][2][64];                // [buf][half][chan]

    const int lane = threadIdx.x & 63;
    const int wave = threadIdx.x >> 6;               // 0..7
    const int bid  = blockIdx.x;                     // 0..511
    const int b    = bid >> 4;                       // 0..31
    const int dgrp = bid & 15;                       // 0..15
    const float* xb = x   + (size_t)b * (T_STEPS * D_DIM) + dgrp * 64;
    float*       ob = out + (size_t)b * (T_STEPS * D_DIM) + dgrp * 64;

    // prologue: producers fill tiles 0,1 (lookahead 2)
    if (wave == 1) load_tile(xb, 0 * T_TILE, lane, tiles[0]);
    if (wave == 2) load_tile(xb, 1 * T_TILE, lane, tiles[1]);
    __syncthreads();

    float v = 0.0f, a = 0.0f;

    for (int k = 0; k <= N_TILES; ++k) {             // 9 pipelined iterations
        if (wave == 0) {
            // ---- consumer: 64 steps of tile k -> 2 packed words in LDS ----
            if (k < N_TILES) {
                unsigned wlo = 0u, whi = 0u;
#pragma unroll
                for (int j = 0; j < T_TILE; ++j) {
                    const float xv = tiles[k % RING][j][lane];
                    const bool f = adlif_step(xv, v, a);
                    if (j < 32) wlo |= ((unsigned)f) << j;
                    else        whi |= ((unsigned)f) << (j - 32);
                }
                sbits[k & 1][0][lane] = wlo;
                sbits[k & 1][1][lane] = whi;
            }
        } else if (wave <= 3) {
            // ---- producer: stage tile k+2 into ring slot (k+2)%3 ----
            const int t = k + 2;
            if (t < N_TILES && wave == (t % 3) + 1)
                load_tile(xb, t * T_TILE, lane, tiles[t % RING]);
        } else {
            // ---- writers: expand tile k-1 bits -> f32, NT float4 stores ----
            if (k >= 1) {
                const int kt = k - 1;
                const int r0 = (wave - 4) * 16;      // this wave's 16 rows
                const int c0 = (lane & 15) * 4;      // 4 channels per lane
                const int rl = lane >> 4;            // 0..3 row-within-instr
                const int half = (r0 >= 32) ? 1 : 0; // wlo or whi
                const unsigned w0 = sbits[kt & 1][half][c0 + 0];
                const unsigned w1 = sbits[kt & 1][half][c0 + 1];
                const unsigned w2 = sbits[kt & 1][half][c0 + 2];
                const unsigned w3 = sbits[kt & 1][half][c0 + 3];
#pragma unroll
                for (int i = 0; i < 4; ++i) {
                    const int r = r0 + i * 4 + rl;   // absolute row in tile
                    const int bitpos = r & 31;
                    f32x4 val;
                    val.x = (float)((w0 >> bitpos) & 1u);
                    val.y = (float)((w1 >> bitpos) & 1u);
                    val.z = (float)((w2 >> bitpos) & 1u);
                    val.w = (float)((w3 >> bitpos) & 1u);
                    __builtin_nontemporal_store(
                        val, (f32x4*)(ob + (size_t)(kt * T_TILE + r) * D_DIM + c0));
                }
            }
        }
        __syncthreads();
    }
}

extern "C" void kernel_launch(void* const* d_in, const int* in_sizes, int n_in,
                              void* d_out, int out_size, void* d_ws, size_t ws_size,
                              hipStream_t stream) {
    const float* x = (const float*)d_in[0];
    float* out = (float*)d_out;

    const int total = in_sizes[0];            // B*T*D = 16777216
    const int channels = total / T_STEPS;     // B*D  = 32768
    const int blocks = channels / 64;         // 512 blocks x 8 waves

    adlif_fused<<<blocks, 512, 0, stream>>>(x, out);
}